// Round 1
// baseline (393.387 us; speedup 1.0000x reference)
//
#include <hip/hip_runtime.h>
#include <math.h>

#define DIM 64
#define FDIM 256   // DIM * H (H=4)

// ---------------- Stage 1: ft = h_v @ W_fc^T + b_fc  -> [N, 256] ----------------
__global__ __launch_bounds__(256) void fc_kernel(const float* __restrict__ h,
                                                 const float* __restrict__ W,
                                                 const float* __restrict__ b,
                                                 float* __restrict__ ft, int N)
{
    const int ROWS = 16;
    __shared__ float hs[ROWS * DIM];
    int t = threadIdx.x;              // output column 0..255
    float w[DIM];
#pragma unroll
    for (int j = 0; j < DIM / 4; ++j) {
        float4 v = *(const float4*)(W + (size_t)t * DIM + j * 4);
        w[4 * j + 0] = v.x; w[4 * j + 1] = v.y;
        w[4 * j + 2] = v.z; w[4 * j + 3] = v.w;
    }
    float bt = b[t];
    int ntiles = (N + ROWS - 1) / ROWS;
    for (int tile = blockIdx.x; tile < ntiles; tile += gridDim.x) {
        int r0 = tile * ROWS;
        int nr = min(ROWS, N - r0);
        __syncthreads();
        int nchunks = nr * DIM / 4;
        for (int i = t; i < nchunks; i += 256)
            ((float4*)hs)[i] = ((const float4*)(h + (size_t)r0 * DIM))[i];
        __syncthreads();
        for (int r = 0; r < nr; ++r) {
            float acc = bt;
#pragma unroll
            for (int k = 0; k < DIM; ++k)
                acc = fmaf(hs[r * DIM + k], w[k], acc);
            ft[(size_t)(r0 + r) * FDIM + t] = acc;
        }
    }
}

// ---------------- Counting sort of edges by dst ----------------
__global__ void zero_kernel(int* __restrict__ p, int n)
{
    int i = blockIdx.x * blockDim.x + threadIdx.x;
    for (; i < n; i += gridDim.x * blockDim.x) p[i] = 0;
}

__global__ void hist_kernel(const int* __restrict__ dst, int* __restrict__ cnt, int E)
{
    int i = blockIdx.x * blockDim.x + threadIdx.x;
    for (; i < E; i += gridDim.x * blockDim.x) atomicAdd(&cnt[dst[i]], 1);
}

__global__ __launch_bounds__(1024) void scan_kernel(const int* __restrict__ cnt,
                                                    int* __restrict__ off,
                                                    int* __restrict__ cur, int N)
{
    __shared__ int part[1024];
    int t = threadIdx.x;
    int chunk = (N + 1023) / 1024;
    int lo = t * chunk, hi = min(lo + chunk, N);
    int sum = 0;
    for (int i = lo; i < hi; ++i) sum += cnt[i];
    part[t] = sum;
    __syncthreads();
    for (int o = 1; o < 1024; o <<= 1) {
        int v = (t >= o) ? part[t - o] : 0;
        __syncthreads();
        part[t] += v;
        __syncthreads();
    }
    int run = (t == 0) ? 0 : part[t - 1];
    for (int i = lo; i < hi; ++i) {
        off[i] = run; cur[i] = run;
        run += cnt[i];
    }
    if (t == 1023) off[N] = run;   // == E (chunks past N are empty)
}

__global__ void scatter_kernel(const int* __restrict__ src, const int* __restrict__ dst,
                               int* __restrict__ cur, int* __restrict__ ssrc, int E)
{
    int i = blockIdx.x * blockDim.x + threadIdx.x;
    for (; i < E; i += gridDim.x * blockDim.x) {
        int d = dst[i];
        int pos = atomicAdd(&cur[d], 1);
        ssrc[pos] = src[i];
    }
}

// ---------------- Fused: score + edge-softmax (online) + weighted sum + head-max ----------------
// One wave (64 lanes) per destination node; lane i owns elements 4i..4i+3 of the 256-dim row.
__global__ __launch_bounds__(256) void agg_kernel(const float* __restrict__ ft,
                                                  const int* __restrict__ off,
                                                  const int* __restrict__ ssrc,
                                                  const float* __restrict__ Wpi,
                                                  float* __restrict__ out, int N)
{
    int wid = (blockIdx.x * blockDim.x + threadIdx.x) >> 6;
    int lane = threadIdx.x & 63;
    if (wid >= N) return;

    const float4 fd = *(const float4*)(ft + (size_t)wid * FDIM + lane * 4);
    const float4 wp = *(const float4*)(Wpi + lane * 4);
    float4 fdw = make_float4(fd.x * wp.x, fd.y * wp.y, fd.z * wp.z, fd.w * wp.w);

    int e0 = off[wid], e1 = off[wid + 1];
    float m = -INFINITY, l = 0.f;
    float4 acc = make_float4(0.f, 0.f, 0.f, 0.f);

    if (e0 < e1) {
        int sv = ssrc[e0];
        float4 fs = *(const float4*)(ft + (size_t)sv * FDIM + lane * 4);
        for (int i = e0; i < e1; ++i) {
            float4 fsn = fs;
            if (i + 1 < e1) {                       // prefetch next row (uniform branch)
                int nv = ssrc[i + 1];
                fsn = *(const float4*)(ft + (size_t)nv * FDIM + lane * 4);
            }
            float p = fs.x * fdw.x + fs.y * fdw.y + fs.z * fdw.z + fs.w * fdw.w;
#pragma unroll
            for (int o = 32; o >= 1; o >>= 1) p += __shfl_xor(p, o, 64);
            float s = p > 0.f ? p : 0.2f * p;       // LeakyReLU(0.2)
            float mn = fmaxf(m, s);
            float sc = __expf(m - mn);              // first iter: exp(-inf)=0
            float pe = __expf(s - mn);
            l = l * sc + pe;
            acc.x = acc.x * sc + pe * fs.x;
            acc.y = acc.y * sc + pe * fs.y;
            acc.z = acc.z * sc + pe * fs.z;
            acc.w = acc.w * sc + pe * fs.w;
            m = mn;
            fs = fsn;
        }
    }
    float inv = (l > 0.f) ? 1.f / l : 0.f;
    float4 r = make_float4(acc.x * inv, acc.y * inv, acc.z * inv, acc.w * inv);
    // head-max: element d = 4*lane+j pairs with lanes ^16 (=+64 elems) and ^32 (=+128)
    r.x = fmaxf(r.x, __shfl_xor(r.x, 16, 64));
    r.y = fmaxf(r.y, __shfl_xor(r.y, 16, 64));
    r.z = fmaxf(r.z, __shfl_xor(r.z, 16, 64));
    r.w = fmaxf(r.w, __shfl_xor(r.w, 16, 64));
    r.x = fmaxf(r.x, __shfl_xor(r.x, 32, 64));
    r.y = fmaxf(r.y, __shfl_xor(r.y, 32, 64));
    r.z = fmaxf(r.z, __shfl_xor(r.z, 32, 64));
    r.w = fmaxf(r.w, __shfl_xor(r.w, 32, 64));
    if (lane < 16)
        *(float4*)(out + (size_t)wid * DIM + lane * 4) = r;
}

extern "C" void kernel_launch(void* const* d_in, const int* in_sizes, int n_in,
                              void* d_out, int out_size, void* d_ws, size_t ws_size,
                              hipStream_t stream)
{
    const float* h_v  = (const float*)d_in[0];
    const int*   src  = (const int*)d_in[1];
    const int*   dst  = (const int*)d_in[2];
    const float* W_fc = (const float*)d_in[3];
    const float* b_fc = (const float*)d_in[4];
    const float* W_pi = (const float*)d_in[5];
    float* out = (float*)d_out;

    int N = in_sizes[0] / DIM;
    int E = in_sizes[1];

    // workspace layout
    float* ft   = (float*)d_ws;
    size_t ftB  = (size_t)N * FDIM * sizeof(float);       // 51.2 MB
    char*  p    = (char*)d_ws + ftB;
    int*   cnt  = (int*)(p);                               // N
    int*   off  = (int*)(p + 256 * 1024);                  // N+1
    int*   cur  = (int*)(p + 512 * 1024);                  // N
    int*   ssrc = (int*)(p + 768 * 1024);                  // E

    int ntiles = (N + 15) / 16;
    fc_kernel<<<ntiles, 256, 0, stream>>>(h_v, W_fc, b_fc, ft, N);
    zero_kernel<<<256, 256, 0, stream>>>(cnt, N);
    hist_kernel<<<1024, 256, 0, stream>>>(dst, cnt, E);
    scan_kernel<<<1, 1024, 0, stream>>>(cnt, off, cur, N);
    scatter_kernel<<<1024, 256, 0, stream>>>(src, dst, cur, ssrc, E);
    int blocks = (N * 64 + 255) / 256;   // one 64-lane wave per node
    agg_kernel<<<blocks, 256, 0, stream>>>(ft, off, ssrc, W_pi, out, N);
}

// Round 2
// 342.066 us; speedup vs baseline: 1.1500x; 1.1500x over previous
//
#include <hip/hip_runtime.h>
#include <math.h>

#define DIM 64
#define FDIM 256   // DIM * H (H=4)

// bf16 (stored as ushort) -> float helpers: elem pair packed in a uint
__device__ __forceinline__ float blo(unsigned int u) {
    union { unsigned int i; float f; } x; x.i = u << 16; return x.f;
}
__device__ __forceinline__ float bhi(unsigned int u) {
    union { unsigned int i; float f; } x; x.i = u & 0xffff0000u; return x.f;
}

// ---------------- Stage 1: ft = bf16(h_v @ W_fc^T + b_fc)  -> [N, 256] ----------------
// Thread t owns output column t; h-row values are wave-uniform (L1/scalar broadcast).
__global__ __launch_bounds__(256) void fc_kernel(const float* __restrict__ h,
                                                 const float* __restrict__ W,
                                                 const float* __restrict__ b,
                                                 unsigned short* __restrict__ ft, int N)
{
    int t = threadIdx.x;              // output column 0..255
    float w[DIM];
#pragma unroll
    for (int j = 0; j < DIM / 4; ++j) {
        float4 v = *(const float4*)(W + (size_t)t * DIM + j * 4);
        w[4 * j + 0] = v.x; w[4 * j + 1] = v.y;
        w[4 * j + 2] = v.z; w[4 * j + 3] = v.w;
    }
    float bt = b[t];
    for (int r = blockIdx.x; r < N; r += gridDim.x) {
        const float4* h4 = (const float4*)(h + (size_t)r * DIM);
        float acc = bt;
#pragma unroll
        for (int j = 0; j < DIM / 4; ++j) {
            float4 hv = h4[j];       // uniform address across the wave
            acc = fmaf(hv.x, w[4 * j + 0], acc);
            acc = fmaf(hv.y, w[4 * j + 1], acc);
            acc = fmaf(hv.z, w[4 * j + 2], acc);
            acc = fmaf(hv.w, w[4 * j + 3], acc);
        }
        union { float f; unsigned int i; } x; x.f = acc;     // RNE to bf16
        unsigned int r16 = (x.i + 0x7fffu + ((x.i >> 16) & 1u)) >> 16;
        ft[(size_t)r * FDIM + t] = (unsigned short)r16;
    }
}

// ---------------- Counting sort of edges by dst ----------------
__global__ void zero_kernel(int* __restrict__ p, int n)
{
    int i = blockIdx.x * blockDim.x + threadIdx.x;
    for (; i < n; i += gridDim.x * blockDim.x) p[i] = 0;
}

__global__ void hist_kernel(const int* __restrict__ dst, int* __restrict__ cnt, int E)
{
    int i = blockIdx.x * blockDim.x + threadIdx.x;
    for (; i < E; i += gridDim.x * blockDim.x) atomicAdd(&cnt[dst[i]], 1);
}

__global__ __launch_bounds__(1024) void scan_kernel(const int* __restrict__ cnt,
                                                    int* __restrict__ off,
                                                    int* __restrict__ cur, int N)
{
    __shared__ int part[1024];
    int t = threadIdx.x;
    int chunk = (N + 1023) / 1024;
    int lo = t * chunk, hi = min(lo + chunk, N);
    int sum = 0;
    for (int i = lo; i < hi; ++i) sum += cnt[i];
    part[t] = sum;
    __syncthreads();
    for (int o = 1; o < 1024; o <<= 1) {
        int v = (t >= o) ? part[t - o] : 0;
        __syncthreads();
        part[t] += v;
        __syncthreads();
    }
    int run = (t == 0) ? 0 : part[t - 1];
    for (int i = lo; i < hi; ++i) {
        off[i] = run; cur[i] = run;
        run += cnt[i];
    }
    if (t == 1023) off[N] = run;   // == E (chunks past N are empty)
}

__global__ void scatter_kernel(const int* __restrict__ src, const int* __restrict__ dst,
                               int* __restrict__ cur, int* __restrict__ ssrc, int E)
{
    int i = blockIdx.x * blockDim.x + threadIdx.x;
    for (; i < E; i += gridDim.x * blockDim.x) {
        int d = dst[i];
        int pos = atomicAdd(&cur[d], 1);
        ssrc[pos] = src[i];
    }
}

// ---------------- Fused: score + edge-softmax (online) + weighted sum + head-max ----------------
// One wave (64 lanes) per destination node; lane i owns elements 4i..4i+3 of the 256-dim row.
// ft is bf16 (ushort); all arithmetic fp32.
__global__ __launch_bounds__(256) void agg_kernel(const unsigned short* __restrict__ ft,
                                                  const int* __restrict__ off,
                                                  const int* __restrict__ ssrc,
                                                  const float* __restrict__ Wpi,
                                                  float* __restrict__ out, int N)
{
    int wid = (blockIdx.x * blockDim.x + threadIdx.x) >> 6;
    int lane = threadIdx.x & 63;
    if (wid >= N) return;

    uint2 dr = *(const uint2*)(ft + (size_t)wid * FDIM + lane * 4);
    const float4 wp = *(const float4*)(Wpi + lane * 4);
    float4 fdw = make_float4(blo(dr.x) * wp.x, bhi(dr.x) * wp.y,
                             blo(dr.y) * wp.z, bhi(dr.y) * wp.w);

    int e0 = off[wid], e1 = off[wid + 1];
    float m = -INFINITY, l = 0.f;
    float4 acc = make_float4(0.f, 0.f, 0.f, 0.f);

    if (e0 < e1) {
        int sv = ssrc[e0];
        uint2 fs = *(const uint2*)(ft + (size_t)sv * FDIM + lane * 4);
        for (int i = e0; i < e1; ++i) {
            uint2 fsn = fs;
            if (i + 1 < e1) {                       // prefetch next row (uniform branch)
                int nv = ssrc[i + 1];
                fsn = *(const uint2*)(ft + (size_t)nv * FDIM + lane * 4);
            }
            float f0 = blo(fs.x), f1 = bhi(fs.x), f2 = blo(fs.y), f3 = bhi(fs.y);
            float p = f0 * fdw.x + f1 * fdw.y + f2 * fdw.z + f3 * fdw.w;
#pragma unroll
            for (int o = 32; o >= 1; o >>= 1) p += __shfl_xor(p, o, 64);
            float s = p > 0.f ? p : 0.2f * p;       // LeakyReLU(0.2)
            float mn = fmaxf(m, s);
            float sc = __expf(m - mn);              // first iter: exp(-inf)=0
            float pe = __expf(s - mn);
            l = l * sc + pe;
            acc.x = acc.x * sc + pe * f0;
            acc.y = acc.y * sc + pe * f1;
            acc.z = acc.z * sc + pe * f2;
            acc.w = acc.w * sc + pe * f3;
            m = mn;
            fs = fsn;
        }
    }
    float inv = (l > 0.f) ? 1.f / l : 0.f;
    float4 r = make_float4(acc.x * inv, acc.y * inv, acc.z * inv, acc.w * inv);
    // head-max: element d = 4*lane+j pairs with lanes ^16 (=+64 elems) and ^32 (=+128)
    r.x = fmaxf(r.x, __shfl_xor(r.x, 16, 64));
    r.y = fmaxf(r.y, __shfl_xor(r.y, 16, 64));
    r.z = fmaxf(r.z, __shfl_xor(r.z, 16, 64));
    r.w = fmaxf(r.w, __shfl_xor(r.w, 16, 64));
    r.x = fmaxf(r.x, __shfl_xor(r.x, 32, 64));
    r.y = fmaxf(r.y, __shfl_xor(r.y, 32, 64));
    r.z = fmaxf(r.z, __shfl_xor(r.z, 32, 64));
    r.w = fmaxf(r.w, __shfl_xor(r.w, 32, 64));
    if (lane < 16)
        *(float4*)(out + (size_t)wid * DIM + lane * 4) = r;
}

extern "C" void kernel_launch(void* const* d_in, const int* in_sizes, int n_in,
                              void* d_out, int out_size, void* d_ws, size_t ws_size,
                              hipStream_t stream)
{
    const float* h_v  = (const float*)d_in[0];
    const int*   src  = (const int*)d_in[1];
    const int*   dst  = (const int*)d_in[2];
    const float* W_fc = (const float*)d_in[3];
    const float* b_fc = (const float*)d_in[4];
    const float* W_pi = (const float*)d_in[5];
    float* out = (float*)d_out;

    int N = in_sizes[0] / DIM;
    int E = in_sizes[1];

    // workspace layout
    unsigned short* ft = (unsigned short*)d_ws;            // N*256*2 = 25.6 MB
    size_t ftB = (((size_t)N * FDIM * 2) + 255) & ~(size_t)255;
    char*  p    = (char*)d_ws + ftB;
    int*   cnt  = (int*)(p);                               // N
    int*   off  = (int*)(p + 256 * 1024);                  // N+1
    int*   cur  = (int*)(p + 512 * 1024);                  // N
    int*   ssrc = (int*)(p + 768 * 1024);                  // E

    fc_kernel<<<1024, 256, 0, stream>>>(h_v, W_fc, b_fc, ft, N);
    zero_kernel<<<256, 256, 0, stream>>>(cnt, N);
    hist_kernel<<<1024, 256, 0, stream>>>(dst, cnt, E);
    scan_kernel<<<1, 1024, 0, stream>>>(cnt, off, cur, N);
    scatter_kernel<<<1024, 256, 0, stream>>>(src, dst, cur, ssrc, E);
    int blocks = (N * 64 + 255) / 256;   // one 64-lane wave per node
    agg_kernel<<<blocks, 256, 0, stream>>>(ft, off, ssrc, W_pi, out, N);
}

// Round 4
// 228.332 us; speedup vs baseline: 1.7229x; 1.4981x over previous
//
#include <hip/hip_runtime.h>
#include <math.h>

#define DIM 64
#define FDIM 256   // DIM * H (H=4)

// bf16 (stored as ushort) -> float helpers: elem pair packed in a uint
__device__ __forceinline__ float blo(unsigned int u) {
    union { unsigned int i; float f; } x; x.i = u << 16; return x.f;
}
__device__ __forceinline__ float bhi(unsigned int u) {
    union { unsigned int i; float f; } x; x.i = u & 0xffff0000u; return x.f;
}

// ---------------- Stage 1: ft = bf16(h_v @ W_fc^T + b_fc)  -> [N, 256] ----------------
// Thread t owns output column t; h-row values are wave-uniform (L1/scalar broadcast).
__global__ __launch_bounds__(256) void fc_kernel(const float* __restrict__ h,
                                                 const float* __restrict__ W,
                                                 const float* __restrict__ b,
                                                 unsigned short* __restrict__ ft, int N)
{
    int t = threadIdx.x;              // output column 0..255
    float w[DIM];
#pragma unroll
    for (int j = 0; j < DIM / 4; ++j) {
        float4 v = *(const float4*)(W + (size_t)t * DIM + j * 4);
        w[4 * j + 0] = v.x; w[4 * j + 1] = v.y;
        w[4 * j + 2] = v.z; w[4 * j + 3] = v.w;
    }
    float bt = b[t];
    for (int r = blockIdx.x; r < N; r += gridDim.x) {
        const float4* h4 = (const float4*)(h + (size_t)r * DIM);
        float acc = bt;
#pragma unroll
        for (int j = 0; j < DIM / 4; ++j) {
            float4 hv = h4[j];       // uniform address across the wave
            acc = fmaf(hv.x, w[4 * j + 0], acc);
            acc = fmaf(hv.y, w[4 * j + 1], acc);
            acc = fmaf(hv.z, w[4 * j + 2], acc);
            acc = fmaf(hv.w, w[4 * j + 3], acc);
        }
        union { float f; unsigned int i; } x; x.f = acc;     // RNE to bf16
        unsigned int r16 = (x.i + 0x7fffu + ((x.i >> 16) & 1u)) >> 16;
        ft[(size_t)r * FDIM + t] = (unsigned short)r16;
    }
}

// ---------------- Counting sort of edges by dst ----------------
__global__ void zero_kernel(int* __restrict__ p, int n)
{
    int i = blockIdx.x * blockDim.x + threadIdx.x;
    for (; i < n; i += gridDim.x * blockDim.x) p[i] = 0;
}

__global__ void hist_kernel(const int* __restrict__ dst, int* __restrict__ cnt, int E)
{
    int i = blockIdx.x * blockDim.x + threadIdx.x;
    for (; i < E; i += gridDim.x * blockDim.x) atomicAdd(&cnt[dst[i]], 1);
}

// Multi-block exclusive scan of cnt[0..N) in 3 phases.
// Phase A: per-block (256 elems) shared-mem scan -> local-exclusive into off, block total into bsum.
__global__ __launch_bounds__(256) void scanA_kernel(const int* __restrict__ cnt,
                                                    int* __restrict__ off,
                                                    int* __restrict__ bsum, int N)
{
    __shared__ int sh[256];
    int t = threadIdx.x;
    int i = blockIdx.x * 256 + t;
    int v = (i < N) ? cnt[i] : 0;
    sh[t] = v;
    __syncthreads();
#pragma unroll
    for (int o = 1; o < 256; o <<= 1) {
        int x = (t >= o) ? sh[t - o] : 0;
        __syncthreads();
        sh[t] += x;
        __syncthreads();
    }
    if (i < N) off[i] = sh[t] - v;          // local exclusive
    if (t == 255) bsum[blockIdx.x] = sh[255];
}

// Phase B: single block, exclusive scan of bsum[0..nb) (nb <= a few hundred), loop with carry.
__global__ __launch_bounds__(256) void scanB_kernel(int* __restrict__ bsum, int nb)
{
    __shared__ int sh[256];
    int t = threadIdx.x;
    int carry = 0;
    for (int base = 0; base < nb; base += 256) {
        int i = base + t;
        int v = (i < nb) ? bsum[i] : 0;
        sh[t] = v;
        __syncthreads();
#pragma unroll
        for (int o = 1; o < 256; o <<= 1) {
            int x = (t >= o) ? sh[t - o] : 0;
            __syncthreads();
            sh[t] += x;
            __syncthreads();
        }
        if (i < nb) bsum[i] = carry + sh[t] - v;   // exclusive
        int tot = sh[255];
        __syncthreads();
        carry += tot;
    }
}

// Phase C: add block offsets, produce final off & cur; off[N] = E.
__global__ void scanC_kernel(int* __restrict__ off, int* __restrict__ cur,
                             const int* __restrict__ bsum, int N, int E)
{
    int i = blockIdx.x * blockDim.x + threadIdx.x;
    if (i < N) {
        int v = off[i] + bsum[i >> 8];
        off[i] = v;
        cur[i] = v;
    }
    if (i == 0) off[N] = E;
}

__global__ void scatter_kernel(const int* __restrict__ src, const int* __restrict__ dst,
                               int* __restrict__ cur, int* __restrict__ ssrc, int E)
{
    int i = blockIdx.x * blockDim.x + threadIdx.x;
    for (; i < E; i += gridDim.x * blockDim.x) {
        int d = dst[i];
        int pos = atomicAdd(&cur[d], 1);
        ssrc[pos] = src[i];
    }
}

// ---------------- Fused: score + edge-softmax (online) + weighted sum + head-max ----------------
// One wave (64 lanes) per destination node; lane i owns elements 4i..4i+3 of the 256-dim row.
// ft is bf16 (ushort); all arithmetic fp32.
__global__ __launch_bounds__(256) void agg_kernel(const unsigned short* __restrict__ ft,
                                                  const int* __restrict__ off,
                                                  const int* __restrict__ ssrc,
                                                  const float* __restrict__ Wpi,
                                                  float* __restrict__ out, int N)
{
    int wid = (blockIdx.x * blockDim.x + threadIdx.x) >> 6;
    int lane = threadIdx.x & 63;
    if (wid >= N) return;

    uint2 dr = *(const uint2*)(ft + (size_t)wid * FDIM + lane * 4);
    const float4 wp = *(const float4*)(Wpi + lane * 4);
    float4 fdw = make_float4(blo(dr.x) * wp.x, bhi(dr.x) * wp.y,
                             blo(dr.y) * wp.z, bhi(dr.y) * wp.w);

    int e0 = off[wid], e1 = off[wid + 1];
    float m = -INFINITY, l = 0.f;
    float4 acc = make_float4(0.f, 0.f, 0.f, 0.f);

    if (e0 < e1) {
        int sv = ssrc[e0];
        uint2 fs = *(const uint2*)(ft + (size_t)sv * FDIM + lane * 4);
        for (int i = e0; i < e1; ++i) {
            uint2 fsn = fs;
            if (i + 1 < e1) {                       // prefetch next row (uniform branch)
                int nv = ssrc[i + 1];
                fsn = *(const uint2*)(ft + (size_t)nv * FDIM + lane * 4);
            }
            float f0 = blo(fs.x), f1 = bhi(fs.x), f2 = blo(fs.y), f3 = bhi(fs.y);
            float p = f0 * fdw.x + f1 * fdw.y + f2 * fdw.z + f3 * fdw.w;
#pragma unroll
            for (int o = 32; o >= 1; o >>= 1) p += __shfl_xor(p, o, 64);
            float s = p > 0.f ? p : 0.2f * p;       // LeakyReLU(0.2)
            float mn = fmaxf(m, s);
            float sc = __expf(m - mn);              // first iter: exp(-inf)=0
            float pe = __expf(s - mn);
            l = l * sc + pe;
            acc.x = acc.x * sc + pe * f0;
            acc.y = acc.y * sc + pe * f1;
            acc.z = acc.z * sc + pe * f2;
            acc.w = acc.w * sc + pe * f3;
            m = mn;
            fs = fsn;
        }
    }
    float inv = (l > 0.f) ? 1.f / l : 0.f;
    float4 r = make_float4(acc.x * inv, acc.y * inv, acc.z * inv, acc.w * inv);
    // head-max: element d = 4*lane+j pairs with lanes ^16 (=+64 elems) and ^32 (=+128)
    r.x = fmaxf(r.x, __shfl_xor(r.x, 16, 64));
    r.y = fmaxf(r.y, __shfl_xor(r.y, 16, 64));
    r.z = fmaxf(r.z, __shfl_xor(r.z, 16, 64));
    r.w = fmaxf(r.w, __shfl_xor(r.w, 16, 64));
    r.x = fmaxf(r.x, __shfl_xor(r.x, 32, 64));
    r.y = fmaxf(r.y, __shfl_xor(r.y, 32, 64));
    r.z = fmaxf(r.z, __shfl_xor(r.z, 32, 64));
    r.w = fmaxf(r.w, __shfl_xor(r.w, 32, 64));
    if (lane < 16)
        *(float4*)(out + (size_t)wid * DIM + lane * 4) = r;
}

extern "C" void kernel_launch(void* const* d_in, const int* in_sizes, int n_in,
                              void* d_out, int out_size, void* d_ws, size_t ws_size,
                              hipStream_t stream)
{
    const float* h_v  = (const float*)d_in[0];
    const int*   src  = (const int*)d_in[1];
    const int*   dst  = (const int*)d_in[2];
    const float* W_fc = (const float*)d_in[3];
    const float* b_fc = (const float*)d_in[4];
    const float* W_pi = (const float*)d_in[5];
    float* out = (float*)d_out;

    int N = in_sizes[0] / DIM;
    int E = in_sizes[1];

    // workspace layout
    unsigned short* ft = (unsigned short*)d_ws;            // N*256*2 = 25.6 MB
    size_t ftB = (((size_t)N * FDIM * 2) + 255) & ~(size_t)255;
    char*  p    = (char*)d_ws + ftB;
    int*   cnt  = (int*)(p);                               // N
    int*   off  = (int*)(p + 256 * 1024);                  // N+1
    int*   cur  = (int*)(p + 512 * 1024);                  // N
    int*   bsum = (int*)(p + 768 * 1024);                  // ceil(N/256)
    int*   ssrc = (int*)(p + 1024 * 1024);                 // E

    int nb = (N + 255) / 256;
    fc_kernel<<<1024, 256, 0, stream>>>(h_v, W_fc, b_fc, ft, N);
    zero_kernel<<<256, 256, 0, stream>>>(cnt, N);
    hist_kernel<<<1024, 256, 0, stream>>>(dst, cnt, E);
    scanA_kernel<<<nb, 256, 0, stream>>>(cnt, off, bsum, N);
    scanB_kernel<<<1, 256, 0, stream>>>(bsum, nb);
    scanC_kernel<<<nb, 256, 0, stream>>>(off, cur, bsum, N, E);
    scatter_kernel<<<1024, 256, 0, stream>>>(src, dst, cur, ssrc, E);
    int blocks = (N * 64 + 255) / 256;   // one 64-lane wave per node
    agg_kernel<<<blocks, 256, 0, stream>>>(ft, off, ssrc, W_pi, out, N);
}